// Round 15
// baseline (52.606 us; speedup 1.0000x reference)
//
#include <hip/hip_runtime.h>
#include <stdint.h>

static constexpr int B = 8, C = 21, H = 512, W = 512;
static constexpr int HW = H * W;            // 262144
static constexpr int N = B * HW;            // 2097152 pixels
static constexpr int CHUNKS = 8;            // best measured geometry (r4/r12/r13)
static constexpr int PPC = HW / CHUNKS;     // 32768 pixels per hist block (2^15: u16-pack safe)
static constexpr int ITER = PPC / 4 / 256;  // 32 float4 iters per thread
static constexpr int NPART = B * CHUNKS;    // 64 partials per class
static constexpr int NB = 1024;             // quantization bound 0.5/NB = 4.9e-4 << 1.77e-2

typedef float v4f __attribute__((ext_vector_type(4)));  // clang ext-vector: valid for NT builtin
                                                        // (compiled+ran r8/r9; r10 proved the
                                                        //  0.574 bug was H-S, NOT NT loads)

// ---------------------------------------------------------------------------
// Pass 1: LDS-privatized per-(class,bucket) histogram (r13 body). ONE change:
// pred (read-once, 176 MB) loaded nontemporally so it stops evicting the
// L2-resident labels (1 MB/image/XCD, re-read 21x) and the slab.
// ---------------------------------------------------------------------------
__global__ __launch_bounds__(256) void hist_kernel(const v4f* __restrict__ pred,
                                                   const int4* __restrict__ lab4,
                                                   unsigned* __restrict__ part,
                                                   unsigned* __restrict__ done,
                                                   int nb, float nbf) {
    int chunk = blockIdx.x;               // 0..CHUNKS-1
    int bc = blockIdx.y;                  // b*C + c
    int b = bc / C, c = bc % C;
    int tid = threadIdx.x;

    if (chunk == 0 && bc == 0 && tid == 0) done[0] = 0u;

    __shared__ unsigned hcnt[NB];
    for (int j = tid; j < nb; j += 256) hcnt[j] = 0;
    __syncthreads();

    const v4f* pp = pred + ((size_t)bc * HW + (size_t)chunk * PPC) / 4;
    const int4* lp = lab4 + ((size_t)b * HW + (size_t)chunk * PPC) / 4;
#pragma unroll 4
    for (int i = 0; i < ITER; ++i) {
        int idx = i * 256 + tid;
        v4f p = __builtin_nontemporal_load(&pp[idx]);
        int4 lv = lp[idx];
        float pe[4] = {p.x, p.y, p.z, p.w};
        int le[4] = {lv.x, lv.y, lv.z, lv.w};
#pragma unroll
        for (int j = 0; j < 4; ++j) {
            unsigned ismatch = (le[j] == c) ? 1u : 0u;
            float e = fabsf((float)ismatch - pe[j]);
            int q = (int)(e * nbf);
            q = q > nb - 1 ? nb - 1 : (q < 0 ? 0 : q);
            atomicAdd(&hcnt[q], 1u | (ismatch << 16));
        }
    }
    __syncthreads();

    unsigned* dst = part + ((size_t)c * NPART + (size_t)(b * CHUNKS + chunk)) * NB;
    for (int j = tid; j < nb; j += 256) dst[j] = hcnt[j];   // coalesced
}

// ---------------------------------------------------------------------------
// Pass 2: one block per class, 1024 threads = one thread per bucket
// (q = NB-1-tid: tid order == descending error). Fold: each thread reads its
// bucket's 64 partials (wave-coalesced, slab L2/L3-resident). Prefix: the
// VALIDATED two-level form (r12/r13; Hillis-Steele was the r8-r10 poison):
// group-of-4 sums -> serial thread-0 exclusive prefix over 256 groups ->
// <=3-term intra-group completion. Telescope per thread:
// e_rep*(J(k2,cg2)-J(k1,cg1)), J(k,cg)=1-(G-cg)/(G+k-cg).
// Finalize fused via the r4/r13 empirically-passing done-counter pattern.
// ---------------------------------------------------------------------------
__global__ __launch_bounds__(1024) void class_kernel(const unsigned* __restrict__ part,
                                                     double* __restrict__ loss_out,
                                                     unsigned long long* __restrict__ g_out,
                                                     unsigned* __restrict__ done,
                                                     float* __restrict__ out) {
    int c = blockIdx.x;
    int tid = threadIdx.x;
    int q = NB - 1 - tid;

    const unsigned* basep = part + (size_t)c * NPART * NB + q;
    unsigned n = 0, g = 0;
#pragma unroll 8
    for (int p = 0; p < NPART; ++p) {
        unsigned v = basep[(size_t)p * NB];
        n += v & 0xffffu;
        g += v >> 16;
    }

    __shared__ unsigned sn[NB], sg[NB];
    sn[tid] = n; sg[tid] = g;
    __syncthreads();

    // level 1: group-of-4 sums (threads 0..255)
    __shared__ unsigned gn[256], gg[256];
    if (tid < 256) {
        unsigned a = 0, b2 = 0;
#pragma unroll
        for (int i = 0; i < 4; ++i) { a += sn[4 * tid + i]; b2 += sg[4 * tid + i]; }
        gn[tid] = a; gg[tid] = b2;
    }
    __syncthreads();

    // level 2: serial exclusive prefix over 256 groups (validated r4/5/6/12/13)
    __shared__ unsigned exn[257], exg[257];
    if (tid == 0) {
        unsigned an = 0, ag = 0;
        for (int i = 0; i < 256; ++i) { exn[i] = an; exg[i] = ag; an += gn[i]; ag += gg[i]; }
        exn[256] = an; exg[256] = ag;
    }
    __syncthreads();

    unsigned G = exg[256];

    // per-thread exclusive prefix: group base + <=3 intra-group predecessors
    unsigned k1u = exn[tid >> 2], cg1u = exg[tid >> 2];
    for (int i = (tid & ~3); i < tid; ++i) { k1u += sn[i]; cg1u += sg[i]; }

    double acc = 0.0;
    if (G > 0 && n > 0) {
        double Gd = (double)G;
        double k1 = (double)k1u, cg1 = (double)cg1u;
        double k2 = k1 + (double)n, cg2 = cg1 + (double)g;
        double jprev = 1.0 - (Gd - cg1) / (Gd + k1 - cg1);
        double jnew  = 1.0 - (Gd - cg2) / (Gd + k2 - cg2);
        acc = (((double)q + 0.5) / (double)NB) * (jnew - jprev);
    }

    __shared__ double red[NB];
    red[tid] = acc;
    __syncthreads();
    for (int s = NB / 2; s > 0; s >>= 1) {
        if (tid < s) red[tid] += red[tid + s];
        __syncthreads();
    }
    if (tid == 0) {
        loss_out[c] = red[0];
        g_out[c] = G;
        __threadfence();                       // publish before signaling (r4/r13 pattern)
        unsigned old = atomicAdd(done, 1u);    // device-scope
        if (old == C - 1) {                    // last class block finalizes
            __threadfence();
            double s = 0.0; int np = 0;
            for (int i = 0; i < C; ++i) {
                unsigned long long gi =
                    __hip_atomic_load(&g_out[i], __ATOMIC_RELAXED, __HIP_MEMORY_SCOPE_AGENT);
                double li =
                    __hip_atomic_load(&loss_out[i], __ATOMIC_RELAXED, __HIP_MEMORY_SCOPE_AGENT);
                if (gi > 0) { s += li; ++np; }
            }
            out[0] = (float)(s / (double)(np > 0 ? np : 1));
        }
    }
}

extern "C" void kernel_launch(void* const* d_in, const int* in_sizes, int n_in,
                              void* d_out, int out_size, void* d_ws, size_t ws_size,
                              hipStream_t stream) {
    const float* pred = (const float*)d_in[0];
    const int* tgt = (const int*)d_in[1];   // int64 narrowed to int32 by harness (validated)
    float* out = (float*)d_out;

    char* ws = (char*)d_ws;
    unsigned* part = (unsigned*)ws;                                  // C*NPART*NB*4 = 5.5 MB
    double* loss = (double*)(ws + (size_t)C * NPART * NB * 4);       // C*8
    unsigned long long* g = (unsigned long long*)(loss + C);         // C*8
    unsigned* done = (unsigned*)(g + C);                             // 4

    hist_kernel<<<dim3(CHUNKS, B * C), dim3(256), 0, stream>>>(
        (const v4f*)pred, (const int4*)tgt, part, done, NB, (float)NB);
    class_kernel<<<dim3(C), dim3(NB), 0, stream>>>(part, loss, g, done, out);
}

// Round 16
// 44.976 us; speedup vs baseline: 1.1696x; 1.1696x over previous
//
#include <hip/hip_runtime.h>
#include <stdint.h>

static constexpr int B = 8, C = 21, H = 512, W = 512;
static constexpr int HW = H * W;            // 262144
static constexpr int N = B * HW;            // 2097152 pixels
static constexpr int CHUNKS = 8;            // best measured geometry (r4/r12/r13)
static constexpr int PPC = HW / CHUNKS;     // 32768 pixels per hist block (2^15: u16-pack safe)
static constexpr int ITER = PPC / 4 / 256;  // 32 float4 iters per thread
static constexpr int NPART = B * CHUNKS;    // 64 partials per class
static constexpr int NB = 1024;             // quantization bound 0.5/NB = 4.9e-4 << 1.77e-2

// ---------------------------------------------------------------------------
// Pass 1: LDS-privatized per-(class,bucket) histogram. EXACT round-13 body
// (measured best: 45.1us). Plain float4 loads — NT loads measured +7.5us
// WORSE (r15). 1344 blocks x 256 thr; packed u32 (count lo16, gt hi16);
// flush = plain coalesced stores; zero global atomics. Block (0,0) zeroes
// the done counter (stream-ordered before pass 2; re-zeroed every replay).
// ---------------------------------------------------------------------------
__global__ __launch_bounds__(256) void hist_kernel(const float4* __restrict__ pred,
                                                   const int4* __restrict__ lab4,
                                                   unsigned* __restrict__ part,
                                                   unsigned* __restrict__ done,
                                                   int nb, float nbf) {
    int chunk = blockIdx.x;               // 0..CHUNKS-1
    int bc = blockIdx.y;                  // b*C + c
    int b = bc / C, c = bc % C;
    int tid = threadIdx.x;

    if (chunk == 0 && bc == 0 && tid == 0) done[0] = 0u;

    __shared__ unsigned hcnt[NB];
    for (int j = tid; j < nb; j += 256) hcnt[j] = 0;
    __syncthreads();

    const float4* pp = pred + ((size_t)bc * HW + (size_t)chunk * PPC) / 4;
    const int4* lp = lab4 + ((size_t)b * HW + (size_t)chunk * PPC) / 4;
#pragma unroll 4
    for (int i = 0; i < ITER; ++i) {
        int idx = i * 256 + tid;
        float4 p = pp[idx];
        int4 lv = lp[idx];
        float pe[4] = {p.x, p.y, p.z, p.w};
        int le[4] = {lv.x, lv.y, lv.z, lv.w};
#pragma unroll
        for (int j = 0; j < 4; ++j) {
            unsigned ismatch = (le[j] == c) ? 1u : 0u;
            float e = fabsf((float)ismatch - pe[j]);
            int q = (int)(e * nbf);
            q = q > nb - 1 ? nb - 1 : (q < 0 ? 0 : q);
            atomicAdd(&hcnt[q], 1u | (ismatch << 16));
        }
    }
    __syncthreads();

    unsigned* dst = part + ((size_t)c * NPART + (size_t)(b * CHUNKS + chunk)) * NB;
    for (int j = tid; j < nb; j += 256) dst[j] = hcnt[j];   // coalesced
}

// ---------------------------------------------------------------------------
// Pass 2: one block per class, 1024 threads = one thread per bucket
// (q = NB-1-tid: tid order == descending error). Fold: each thread reads its
// bucket's 64 partials (wave-coalesced, slab L2/L3-resident). Prefix: the
// VALIDATED two-level form (r12/r13; Hillis-Steele was the r8-r10 poison):
// group-of-4 sums -> serial thread-0 exclusive prefix over 256 groups ->
// <=3-term intra-group completion. Telescope per thread:
// e_rep*(J(k2,cg2)-J(k1,cg1)), J(k,cg)=1-(G-cg)/(G+k-cg).
// Finalize fused via the r4/r13 empirically-passing done-counter pattern.
// ---------------------------------------------------------------------------
__global__ __launch_bounds__(1024) void class_kernel(const unsigned* __restrict__ part,
                                                     double* __restrict__ loss_out,
                                                     unsigned long long* __restrict__ g_out,
                                                     unsigned* __restrict__ done,
                                                     float* __restrict__ out) {
    int c = blockIdx.x;
    int tid = threadIdx.x;
    int q = NB - 1 - tid;

    const unsigned* basep = part + (size_t)c * NPART * NB + q;
    unsigned n = 0, g = 0;
#pragma unroll 8
    for (int p = 0; p < NPART; ++p) {
        unsigned v = basep[(size_t)p * NB];
        n += v & 0xffffu;
        g += v >> 16;
    }

    __shared__ unsigned sn[NB], sg[NB];
    sn[tid] = n; sg[tid] = g;
    __syncthreads();

    // level 1: group-of-4 sums (threads 0..255)
    __shared__ unsigned gn[256], gg[256];
    if (tid < 256) {
        unsigned a = 0, b2 = 0;
#pragma unroll
        for (int i = 0; i < 4; ++i) { a += sn[4 * tid + i]; b2 += sg[4 * tid + i]; }
        gn[tid] = a; gg[tid] = b2;
    }
    __syncthreads();

    // level 2: serial exclusive prefix over 256 groups (validated r4/5/6/12/13)
    __shared__ unsigned exn[257], exg[257];
    if (tid == 0) {
        unsigned an = 0, ag = 0;
        for (int i = 0; i < 256; ++i) { exn[i] = an; exg[i] = ag; an += gn[i]; ag += gg[i]; }
        exn[256] = an; exg[256] = ag;
    }
    __syncthreads();

    unsigned G = exg[256];

    // per-thread exclusive prefix: group base + <=3 intra-group predecessors
    unsigned k1u = exn[tid >> 2], cg1u = exg[tid >> 2];
    for (int i = (tid & ~3); i < tid; ++i) { k1u += sn[i]; cg1u += sg[i]; }

    double acc = 0.0;
    if (G > 0 && n > 0) {
        double Gd = (double)G;
        double k1 = (double)k1u, cg1 = (double)cg1u;
        double k2 = k1 + (double)n, cg2 = cg1 + (double)g;
        double jprev = 1.0 - (Gd - cg1) / (Gd + k1 - cg1);
        double jnew  = 1.0 - (Gd - cg2) / (Gd + k2 - cg2);
        acc = (((double)q + 0.5) / (double)NB) * (jnew - jprev);
    }

    __shared__ double red[NB];
    red[tid] = acc;
    __syncthreads();
    for (int s = NB / 2; s > 0; s >>= 1) {
        if (tid < s) red[tid] += red[tid + s];
        __syncthreads();
    }
    if (tid == 0) {
        loss_out[c] = red[0];
        g_out[c] = G;
        __threadfence();                       // publish before signaling (r4/r13 pattern)
        unsigned old = atomicAdd(done, 1u);    // device-scope
        if (old == C - 1) {                    // last class block finalizes
            __threadfence();
            double s = 0.0; int np = 0;
            for (int i = 0; i < C; ++i) {
                unsigned long long gi =
                    __hip_atomic_load(&g_out[i], __ATOMIC_RELAXED, __HIP_MEMORY_SCOPE_AGENT);
                double li =
                    __hip_atomic_load(&loss_out[i], __ATOMIC_RELAXED, __HIP_MEMORY_SCOPE_AGENT);
                if (gi > 0) { s += li; ++np; }
            }
            out[0] = (float)(s / (double)(np > 0 ? np : 1));
        }
    }
}

extern "C" void kernel_launch(void* const* d_in, const int* in_sizes, int n_in,
                              void* d_out, int out_size, void* d_ws, size_t ws_size,
                              hipStream_t stream) {
    const float* pred = (const float*)d_in[0];
    const int* tgt = (const int*)d_in[1];   // int64 narrowed to int32 by harness (validated)
    float* out = (float*)d_out;

    char* ws = (char*)d_ws;
    unsigned* part = (unsigned*)ws;                                  // C*NPART*NB*4 = 5.5 MB
    double* loss = (double*)(ws + (size_t)C * NPART * NB * 4);       // C*8
    unsigned long long* g = (unsigned long long*)(loss + C);         // C*8
    unsigned* done = (unsigned*)(g + C);                             // 4

    hist_kernel<<<dim3(CHUNKS, B * C), dim3(256), 0, stream>>>(
        (const float4*)pred, (const int4*)tgt, part, done, NB, (float)NB);
    class_kernel<<<dim3(C), dim3(NB), 0, stream>>>(part, loss, g, done, out);
}